// Round 4
// baseline (341.048 us; speedup 1.0000x reference)
//
#include <hip/hip_runtime.h>

// CIN factored: out[b,o,d] = relu(bias[o] + sum_hh h[b,hh,d] * Y_hh[o,d]),
//   Y_hh[o,d] = sum_m W[o,hh,m] * x0[b,m,d]   (MFMA, 3-term bf16 split on W,x0)
// No LDS anywhere: h enters via 16-dword broadcast global reads (L1/L2-hot),
// prefetched 2 steps ahead; W A-frags prefetched 2 steps ahead.
// B=512, M=32, D=64, O=128/layer, H = 32/128/128.

constexpr int Bb = 512, Mm = 32, Dd = 64, Oo = 128, RES = 384;

typedef __attribute__((ext_vector_type(8))) short bf16x8;
typedef __attribute__((ext_vector_type(4))) float f32x4;

static __device__ __forceinline__ ushort f2bf(float f) {
  union { float f; uint u; } v;
  v.f = f;
  uint u = v.u;
  return (ushort)((u + 0x7FFFu + ((u >> 16) & 1u)) >> 16);  // RNE
}
static __device__ __forceinline__ float bf2f(ushort b) {
  union { uint u; float f; } v;
  v.u = (uint)b << 16;
  return v.f;
}

// W[o][hh*32+m] -> A-frag planes [hh][f][lane][j]: o=f*16+(lane&15), m=(lane>>4)*8+j
static __device__ __forceinline__ void wsplit_one(const float* __restrict__ W,
                                                  ushort* __restrict__ Whi,
                                                  ushort* __restrict__ Wlo,
                                                  int H, int t) {
  int l = t & 63, fo = (t >> 6) & 7, hh = t >> 9;
  int o = fo * 16 + (l & 15);
  int m0 = (l >> 4) * 8;
  const float* src = W + (size_t)o * (H * 32) + hh * 32 + m0;
  ushort hi[8], lo[8];
#pragma unroll
  for (int j = 0; j < 8; ++j) {
    float w = src[j];
    ushort h = f2bf(w);
    hi[j] = h;
    lo[j] = f2bf(w - bf2f(h));
  }
  *reinterpret_cast<uint4*>(Whi + (size_t)t * 8) = *reinterpret_cast<uint4*>(hi);
  *reinterpret_cast<uint4*>(Wlo + (size_t)t * 8) = *reinterpret_cast<uint4*>(lo);
}

// x0[b][m][d] -> B-frag planes [b][fd][lane][j]: m=(lane>>4)*8+j, d=fd*16+(lane&15)
static __device__ __forceinline__ void x0split_one(const float* __restrict__ x0,
                                                   ushort* __restrict__ Xhi,
                                                   ushort* __restrict__ Xlo, int t) {
  int l = t & 63, fd = (t >> 6) & 3, b = t >> 8;
  int d = fd * 16 + (l & 15);
  int m0 = (l >> 4) * 8;
  const float* src = x0 + ((size_t)b * Mm + m0) * Dd + d;
  ushort hi[8], lo[8];
#pragma unroll
  for (int j = 0; j < 8; ++j) {
    float w = src[j * Dd];
    ushort h = f2bf(w);
    hi[j] = h;
    lo[j] = f2bf(w - bf2f(h));
  }
  *reinterpret_cast<uint4*>(Xhi + (size_t)t * 8) = *reinterpret_cast<uint4*>(hi);
  *reinterpret_cast<uint4*>(Xlo + (size_t)t * 8) = *reinterpret_cast<uint4*>(lo);
}

// One fused prep kernel: W0 | W1 | W2 | x0 segments.
__global__ __launch_bounds__(256) void prep_kernel(
    const float* __restrict__ W0, const float* __restrict__ W1,
    const float* __restrict__ W2, const float* __restrict__ x0,
    ushort* __restrict__ Whi0, ushort* __restrict__ Wlo0,
    ushort* __restrict__ Whi1, ushort* __restrict__ Wlo1,
    ushort* __restrict__ Whi2, ushort* __restrict__ Wlo2,
    ushort* __restrict__ Xhi, ushort* __restrict__ Xlo) {
  int t = blockIdx.x * 256 + threadIdx.x;
  if (t < 16384) {
    wsplit_one(W0, Whi0, Wlo0, 32, t);
  } else if (t < 81920) {
    wsplit_one(W1, Whi1, Wlo1, 128, t - 16384);
  } else if (t < 147456) {
    wsplit_one(W2, Whi2, Wlo2, 128, t - 81920);
  } else {
    x0split_one(x0, Xhi, Xlo, t - 147456);
  }
}

template <int H>
__global__ __launch_bounds__(256, 4) void cin_mfma_kernel(
    const float* __restrict__ h_in,   // [512,H,64] fp32
    const ushort* __restrict__ Whi,   // [H][8][64][8]
    const ushort* __restrict__ Wlo,
    const ushort* __restrict__ Xhi,   // [512][4][64][8]
    const ushort* __restrict__ Xlo,
    const float* __restrict__ bias,   // [128]
    float* __restrict__ h_out,        // [512,128,64] or nullptr
    float* __restrict__ res,          // [512,384]
    int res_off) {
  const int b = blockIdx.x;
  const int q = blockIdx.y;  // o-half
  const int t = threadIdx.x;
  const int lane = t & 63;
  const int f = __builtin_amdgcn_readfirstlane(q * 4 + (t >> 6));  // A-frag idx
  const int cid = lane & 15;

  // x0 B-fragments, register-resident for the whole kernel
  bf16x8 xh[4], xl[4];
#pragma unroll
  for (int fd = 0; fd < 4; ++fd) {
    size_t off = (((size_t)b * 4 + fd) * 64 + lane) * 8;
    xh[fd] = *reinterpret_cast<const bf16x8*>(Xhi + off);
    xl[fd] = *reinterpret_cast<const bf16x8*>(Xlo + off);
  }

  const float* hb = h_in + (size_t)b * H * Dd + cid;  // + hh*64 + fd*16
  const size_t hstride = (size_t)8 * 64 * 8;          // ushorts per hh
  const ushort* pwh = Whi + ((size_t)f * 64 + lane) * 8;
  const ushort* pwl = Wlo + ((size_t)f * 64 + lane) * 8;

  const f32x4 kZ = {0.f, 0.f, 0.f, 0.f};
  f32x4 acc[4];
#pragma unroll
  for (int fd = 0; fd < 4; ++fd) acc[fd] = kZ;

  // 2-deep prefetch state (even/odd hh slots)
  bf16x8 aAh = *reinterpret_cast<const bf16x8*>(pwh);
  bf16x8 aAl = *reinterpret_cast<const bf16x8*>(pwl);
  bf16x8 aBh = *reinterpret_cast<const bf16x8*>(pwh + hstride);
  bf16x8 aBl = *reinterpret_cast<const bf16x8*>(pwl + hstride);
  float hvA[4], hvB[4];
#pragma unroll
  for (int fd = 0; fd < 4; ++fd) {
    hvA[fd] = hb[fd * 16];
    hvB[fd] = hb[Dd + fd * 16];
  }

#pragma unroll 1
  for (int hh = 0; hh < H; hh += 2) {
    const int hnA = (hh + 2 < H) ? hh + 2 : hh;      // clamped (safe) prefetch
    const int hnB = (hh + 3 < H) ? hh + 3 : hh + 1;

    // ---- even hh ----
    f32x4 y[4];
#pragma unroll
    for (int fd = 0; fd < 4; ++fd)
      y[fd] = __builtin_amdgcn_mfma_f32_16x16x32_bf16(aAh, xh[fd], kZ, 0, 0, 0);
#pragma unroll
    for (int fd = 0; fd < 4; ++fd)
      y[fd] = __builtin_amdgcn_mfma_f32_16x16x32_bf16(aAh, xl[fd], y[fd], 0, 0, 0);
#pragma unroll
    for (int fd = 0; fd < 4; ++fd)
      y[fd] = __builtin_amdgcn_mfma_f32_16x16x32_bf16(aAl, xh[fd], y[fd], 0, 0, 0);
    // prefetch hh+2 (A frags + h values) while MFMAs drain
    aAh = *reinterpret_cast<const bf16x8*>(pwh + (size_t)hnA * hstride);
    aAl = *reinterpret_cast<const bf16x8*>(pwl + (size_t)hnA * hstride);
    float nhvA[4];
#pragma unroll
    for (int fd = 0; fd < 4; ++fd) nhvA[fd] = hb[hnA * Dd + fd * 16];
#pragma unroll
    for (int fd = 0; fd < 4; ++fd)
#pragma unroll
      for (int r = 0; r < 4; ++r) acc[fd][r] = fmaf(hvA[fd], y[fd][r], acc[fd][r]);
#pragma unroll
    for (int fd = 0; fd < 4; ++fd) hvA[fd] = nhvA[fd];

    // ---- odd hh ----
    f32x4 z[4];
#pragma unroll
    for (int fd = 0; fd < 4; ++fd)
      z[fd] = __builtin_amdgcn_mfma_f32_16x16x32_bf16(aBh, xh[fd], kZ, 0, 0, 0);
#pragma unroll
    for (int fd = 0; fd < 4; ++fd)
      z[fd] = __builtin_amdgcn_mfma_f32_16x16x32_bf16(aBh, xl[fd], z[fd], 0, 0, 0);
#pragma unroll
    for (int fd = 0; fd < 4; ++fd)
      z[fd] = __builtin_amdgcn_mfma_f32_16x16x32_bf16(aBl, xh[fd], z[fd], 0, 0, 0);
    aBh = *reinterpret_cast<const bf16x8*>(pwh + (size_t)hnB * hstride);
    aBl = *reinterpret_cast<const bf16x8*>(pwl + (size_t)hnB * hstride);
    float nhvB[4];
#pragma unroll
    for (int fd = 0; fd < 4; ++fd) nhvB[fd] = hb[hnB * Dd + fd * 16];
#pragma unroll
    for (int fd = 0; fd < 4; ++fd)
#pragma unroll
      for (int r = 0; r < 4; ++r) acc[fd][r] = fmaf(hvB[fd], z[fd][r], acc[fd][r]);
#pragma unroll
    for (int fd = 0; fd < 4; ++fd) hvB[fd] = nhvB[fd];
  }

  // epilogue: bias + relu, write h_out, reduce over d into res
  const int rg = lane >> 4;
#pragma unroll
  for (int r = 0; r < 4; ++r) {
    int o = f * 16 + rg * 4 + r;
    float bs = bias[o];
    float sd = 0.f;
#pragma unroll
    for (int fd = 0; fd < 4; ++fd) {
      float v = acc[fd][r] + bs;
      v = v > 0.f ? v : 0.f;
      if (h_out != nullptr) h_out[((size_t)b * Oo + o) * Dd + fd * 16 + cid] = v;
      sd += v;
    }
#pragma unroll
    for (int mk = 1; mk < 16; mk <<= 1) sd += __shfl_xor(sd, mk, 64);
    if (cid == 0) res[(size_t)b * RES + res_off + o] = sd;
  }
}

__global__ __launch_bounds__(64) void cin_score_kernel(
    const float* __restrict__ res, const float* __restrict__ lw,
    const float* __restrict__ lb, float* __restrict__ out) {
  const int b = blockIdx.x;
  const int lane = threadIdx.x;
  float acc = 0.f;
#pragma unroll
  for (int i = 0; i < RES / 64; ++i) {
    const int idx = i * 64 + lane;
    acc = fmaf(res[b * RES + idx], lw[idx], acc);
  }
#pragma unroll
  for (int off = 32; off >= 1; off >>= 1) acc += __shfl_xor(acc, off, 64);
  if (lane == 0) out[b] = acc + lb[0];
}

extern "C" void kernel_launch(void* const* d_in, const int* in_sizes, int n_in,
                              void* d_out, int out_size, void* d_ws, size_t ws_size,
                              hipStream_t stream) {
  const float* x0 = (const float*)d_in[0];
  const float* W0 = (const float*)d_in[1];
  const float* b0 = (const float*)d_in[2];
  const float* W1 = (const float*)d_in[3];
  const float* b1 = (const float*)d_in[4];
  const float* W2 = (const float*)d_in[5];
  const float* b2 = (const float*)d_in[6];
  const float* lw = (const float*)d_in[7];
  const float* lb = (const float*)d_in[8];
  float* out = (float*)d_out;

  float* h1 = (float*)d_ws;                // 512*128*64 f32 (16 MiB)
  float* h2 = h1 + (size_t)Bb * Oo * Dd;   // 16 MiB
  float* res = h2 + (size_t)Bb * Oo * Dd;  // 512*384 f32
  ushort* Whi0 = (ushort*)(res + (size_t)Bb * RES);
  ushort* Wlo0 = Whi0 + (size_t)32 * 8 * 64 * 8;
  ushort* Whi1 = Wlo0 + (size_t)32 * 8 * 64 * 8;
  ushort* Wlo1 = Whi1 + (size_t)128 * 8 * 64 * 8;
  ushort* Whi2 = Wlo1 + (size_t)128 * 8 * 64 * 8;
  ushort* Wlo2 = Whi2 + (size_t)128 * 8 * 64 * 8;
  ushort* Xhi = Wlo2 + (size_t)128 * 8 * 64 * 8;
  ushort* Xlo = Xhi + (size_t)Bb * 4 * 64 * 8;

  prep_kernel<<<dim3(1088), dim3(256), 0, stream>>>(W0, W1, W2, x0, Whi0, Wlo0,
                                                    Whi1, Wlo1, Whi2, Wlo2, Xhi, Xlo);

  cin_mfma_kernel<32><<<dim3(Bb, 2), dim3(256), 0, stream>>>(x0, Whi0, Wlo0, Xhi, Xlo, b0, h1, res, 0);
  cin_mfma_kernel<128><<<dim3(Bb, 2), dim3(256), 0, stream>>>(h1, Whi1, Wlo1, Xhi, Xlo, b1, h2, res, 128);
  cin_mfma_kernel<128><<<dim3(Bb, 2), dim3(256), 0, stream>>>(h2, Whi2, Wlo2, Xhi, Xlo, b2, nullptr, res, 256);

  cin_score_kernel<<<dim3(Bb), dim3(64), 0, stream>>>(res, lw, lb, out);
}